// Round 1
// baseline (1003.694 us; speedup 1.0000x reference)
//
#include <hip/hip_runtime.h>

#define NN   2048   // nodes per sample
#define KNN  16     // neighbors
#define BATCH 8

// ---------------------------------------------------------------------------
// Kernel 1: exact kNN (K=16) on first 3 coordinate dims, per sample.
// One thread per node; all 2048 points (xyz + |p|^2) staged in LDS (32 KB).
// Top-16 kept in registers with a fully unrolled insertion list (static
// indices only -> stays in VGPRs). Strict '<' on replacement preserves
// lax.top_k's lowest-index tie-break.
// ---------------------------------------------------------------------------
__global__ __launch_bounds__(256) void knn_kernel(const float* __restrict__ coords,
                                                  int* __restrict__ nbr) {
  __shared__ float sx[NN], sy[NN], sz[NN], ssq[NN];
  const int b = blockIdx.x >> 3;            // 8 node-blocks of 256 per sample
  const int nodeBase = (blockIdx.x & 7) << 8;
  const float* cb = coords + (size_t)b * NN * 6;
  for (int j = threadIdx.x; j < NN; j += 256) {
    float x = cb[j * 6 + 0];
    float y = cb[j * 6 + 1];
    float z = cb[j * 6 + 2];
    sx[j] = x; sy[j] = y; sz[j] = z;
    ssq[j] = x * x + y * y + z * z;
  }
  __syncthreads();

  const int i = nodeBase + (int)threadIdx.x;
  const float xi = sx[i], yi = sy[i], zi = sz[i], sqi = ssq[i];

  float bd[KNN];
  int   bi[KNN];
#pragma unroll
  for (int k = 0; k < KNN; ++k) { bd[k] = 1e30f; bi[k] = 0; }

  for (int j = 0; j < NN; ++j) {
    // same algebraic form as the reference: sq_i + sq_j - 2*dot
    float dot = xi * sx[j] + yi * sy[j] + zi * sz[j];
    float d2  = (sqi + ssq[j]) - 2.0f * dot;
    if (d2 < bd[KNN - 1] && j != i) {
      bd[KNN - 1] = d2;
      bi[KNN - 1] = j;
#pragma unroll
      for (int k = KNN - 1; k > 0; --k) {
        if (bd[k] < bd[k - 1]) {
          float td = bd[k]; bd[k] = bd[k - 1]; bd[k - 1] = td;
          int   ti = bi[k]; bi[k] = bi[k - 1]; bi[k - 1] = ti;
        }
      }
    }
  }

  int* on = nbr + ((size_t)b * NN + i) * KNN;
#pragma unroll
  for (int k = 0; k < KNN; ++k) on[k] = bi[k];
}

// ---------------------------------------------------------------------------
// Kernel 2: tiny row-major GEMM  H[n, :] = X[n, :] @ W (+ bias).
// One thread computes 4 consecutive outputs with float4 weight loads.
// X row stride == IN for every layer here (coords stride 6 == IN of layer 1).
// ---------------------------------------------------------------------------
template <int IN, int OUT, bool HASBIAS>
__global__ __launch_bounds__(256) void matmul_kernel(const float* __restrict__ X,
                                                     const float* __restrict__ W,
                                                     const float* __restrict__ bias,
                                                     float* __restrict__ H) {
  constexpr int PER = OUT / 4;
  const int t = blockIdx.x * 256 + (int)threadIdx.x;
  if (t >= BATCH * NN * PER) return;
  const int og = (t % PER) * 4;
  const int n  = t / PER;

  const float* x = X + (size_t)n * IN;
  float ax = 0.f, ay = 0.f, az = 0.f, aw = 0.f;
#pragma unroll
  for (int c = 0; c < IN; ++c) {
    const float xv = x[c];
    const float4 wv = *reinterpret_cast<const float4*>(W + c * OUT + og);
    ax += xv * wv.x; ay += xv * wv.y; az += xv * wv.z; aw += xv * wv.w;
  }
  if (HASBIAS) {
    ax += bias[og + 0]; ay += bias[og + 1]; az += bias[og + 2]; aw += bias[og + 3];
  }
  float4 r; r.x = ax; r.y = ay; r.z = az; r.w = aw;
  *reinterpret_cast<float4*>(H + (size_t)n * OUT + og) = r;
}

// ---------------------------------------------------------------------------
// Kernel 3: GCN aggregation  Y[n,:] = relu((sum_k H[nbr[n,k],:] + H[n,:])/17 + b)
// One thread per (node, 4 outputs); 16 coalesced float4 gathers.
// ---------------------------------------------------------------------------
template <int OUT>
__global__ __launch_bounds__(256) void agg_kernel(const float* __restrict__ H,
                                                  const int* __restrict__ nbr,
                                                  const float* __restrict__ bias,
                                                  float* __restrict__ Y) {
  constexpr int PER = OUT / 4;
  const int t = blockIdx.x * 256 + (int)threadIdx.x;
  if (t >= BATCH * NN * PER) return;
  const int og = (t % PER) * 4;
  const int n  = t / PER;
  const int b  = n >> 11;  // n / NN

  const int* nb = nbr + (size_t)n * KNN;
  const float* Hb = H + (((size_t)b) << 11) * OUT;

  float sx = 0.f, sy = 0.f, sz = 0.f, sw = 0.f;
#pragma unroll
  for (int k = 0; k < KNN; ++k) {
    const int idx = nb[k];
    const float4 v = *reinterpret_cast<const float4*>(Hb + (size_t)idx * OUT + og);
    sx += v.x; sy += v.y; sz += v.z; sw += v.w;
  }
  const float4 h = *reinterpret_cast<const float4*>(H + (size_t)n * OUT + og);
  sx += h.x; sy += h.y; sz += h.z; sw += h.w;

  const float sc = 1.0f / 17.0f;
  float4 r;
  r.x = fmaxf(sx * sc + bias[og + 0], 0.f);
  r.y = fmaxf(sy * sc + bias[og + 1], 0.f);
  r.z = fmaxf(sz * sc + bias[og + 2], 0.f);
  r.w = fmaxf(sw * sc + bias[og + 3], 0.f);
  *reinterpret_cast<float4*>(Y + (size_t)n * OUT + og) = r;
}

// ---------------------------------------------------------------------------
extern "C" void kernel_launch(void* const* d_in, const int* in_sizes, int n_in,
                              void* d_out, int out_size, void* d_ws, size_t ws_size,
                              hipStream_t stream) {
  const float* coords = (const float*)d_in[0];
  const float* W1 = (const float*)d_in[1];
  const float* b1 = (const float*)d_in[2];
  const float* W2 = (const float*)d_in[3];
  const float* b2 = (const float*)d_in[4];
  const float* Wf = (const float*)d_in[5];
  const float* bf = (const float*)d_in[6];
  float* out = (float*)d_out;

  char* ws = (char*)d_ws;
  // ws layout (25 MB total):
  //   nbr : [8*2048*16] int    @ 0        (1 MB)
  //   h1  : [8*2048*64] float  @ 1 MB     (4 MB)
  //   x1  : [8*2048*64] float  @ 5 MB     (4 MB)
  //   h2  : [8*2048*128] float @ 9 MB     (8 MB)
  //   x2  : [8*2048*128] float @ 17 MB    (8 MB)
  int*   nbr = (int*)ws;
  float* h1  = (float*)(ws + (size_t)(1u << 20) * 1);
  float* x1  = (float*)(ws + (size_t)(1u << 20) * 5);
  float* h2  = (float*)(ws + (size_t)(1u << 20) * 9);
  float* x2  = (float*)(ws + (size_t)(1u << 20) * 17);

  const int totalN = BATCH * NN;  // 16384

  knn_kernel<<<BATCH * (NN / 256), 256, 0, stream>>>(coords, nbr);

  matmul_kernel<6, 64, false><<<(totalN * (64 / 4)) / 256, 256, 0, stream>>>(coords, W1, nullptr, h1);
  agg_kernel<64><<<(totalN * (64 / 4)) / 256, 256, 0, stream>>>(h1, nbr, b1, x1);

  matmul_kernel<64, 128, false><<<(totalN * (128 / 4)) / 256, 256, 0, stream>>>(x1, W2, nullptr, h2);
  agg_kernel<128><<<(totalN * (128 / 4)) / 256, 256, 0, stream>>>(h2, nbr, b2, x2);

  matmul_kernel<128, 128, true><<<(totalN * (128 / 4)) / 256, 256, 0, stream>>>(x2, Wf, bf, out);
}

// Round 2
// 243.206 us; speedup vs baseline: 4.1269x; 4.1269x over previous
//
#include <hip/hip_runtime.h>

#define NN    2048   // nodes per sample
#define KNN   16     // neighbors
#define BATCH 8

// ---------------------------------------------------------------------------
// 64-bit broadcast from a (uniform) lane via v_readlane (no LDS-path latency).
// ---------------------------------------------------------------------------
__device__ __forceinline__ unsigned long long bcast64(unsigned long long v, int l) {
  unsigned lo = __builtin_amdgcn_readlane((unsigned)(v & 0xffffffffu), l);
  unsigned hi = __builtin_amdgcn_readlane((unsigned)(v >> 32), l);
  return ((unsigned long long)hi << 32) | lo;
}

__device__ __forceinline__ unsigned long long shflup1_64(unsigned long long v) {
  unsigned lo = __shfl_up((unsigned)(v & 0xffffffffu), 1);
  unsigned hi = __shfl_up((unsigned)(v >> 32), 1);
  return ((unsigned long long)hi << 32) | lo;
}

// ---------------------------------------------------------------------------
// Kernel 1: exact kNN (K=16), one WAVE per node.
// Top-16 list lives distributed: lane k (k<16) holds the k-th smallest key,
// key = (sortable_f32(d2) << 32) | j  -> strict-less == top_k lowest-index
// tie-break. Output order is irrelevant (consumed by a sum).
// Per 64-candidate batch: 1 distance/lane, ballot against the (uniform)
// 16th-best key, then a uniform loop over surviving lanes; each insertion is
// a shfl_up shift + cndmask (~10 ops), no divergence anywhere.
// ---------------------------------------------------------------------------
__global__ __launch_bounds__(256) void knn_kernel(const float* __restrict__ coords,
                                                  int* __restrict__ nbr) {
  __shared__ float4 sP[NN];  // x,y,z,|p|^2  (32 KB)

  const int b        = blockIdx.x >> 9;          // 512 blocks per sample
  const int nodeBase = (blockIdx.x & 511) << 2;  // 4 nodes per block
  const int lane     = (int)threadIdx.x & 63;
  const int wid      = (int)threadIdx.x >> 6;

  const float* cb = coords + (size_t)b * NN * 6;
  for (int p = threadIdx.x; p < NN; p += 256) {
    float x = cb[p * 6 + 0];
    float y = cb[p * 6 + 1];
    float z = cb[p * 6 + 2];
    float4 v; v.x = x; v.y = y; v.z = z; v.w = x * x + y * y + z * z;
    sP[p] = v;
  }
  __syncthreads();

  const int i = nodeBase + wid;
  const float4 pi = sP[i];
  const float xi = pi.x, yi = pi.y, zi = pi.z, sqi = pi.w;

  unsigned long long lk  = ~0ull;  // this lane's list element (lanes 0..15 meaningful)
  unsigned long long kth = ~0ull;  // broadcast of lane 15's element

  for (int t = 0; t < NN; t += 64) {
    const int j = t + lane;
    const float4 pj = sP[j];
    const float d2 = (sqi + pj.w) - 2.0f * (xi * pj.x + yi * pj.y + zi * pj.z);
    // monotonic float->uint key; index in low bits for top_k tie-break
    unsigned u   = __float_as_uint(d2);
    unsigned k32 = u ^ (unsigned)((((int)u) >> 31) | 0x80000000);
    unsigned long long ck = ((unsigned long long)k32 << 32) | (unsigned)j;

    unsigned long long mask = __ballot(ck < kth && j != i);
    while (mask) {
      const int src = __ffsll(mask) - 1;
      mask &= mask - 1;
      const unsigned long long c = bcast64(ck, src);  // uniform
      if (c < kth) {                                   // uniform branch
        unsigned long long pk = shflup1_64(lk);
        if (lane == 0) pk = 0ull;  // -inf sentinel (real keys are > 0)
        lk  = (lk < c) ? lk : (pk < c ? c : pk);       // sorted shift-insert
        kth = bcast64(lk, 15);
      }
    }
  }

  if (lane < KNN) {
    nbr[((size_t)b * NN + i) * KNN + lane] = (int)(lk & 0xffffffffu);
  }
}

// ---------------------------------------------------------------------------
// Kernel 2: tiny row-major GEMM  H[n, :] = X[n, :] @ W (+ bias).
// ---------------------------------------------------------------------------
template <int IN, int OUT, bool HASBIAS>
__global__ __launch_bounds__(256) void matmul_kernel(const float* __restrict__ X,
                                                     const float* __restrict__ W,
                                                     const float* __restrict__ bias,
                                                     float* __restrict__ H) {
  constexpr int PER = OUT / 4;
  const int t = blockIdx.x * 256 + (int)threadIdx.x;
  if (t >= BATCH * NN * PER) return;
  const int og = (t % PER) * 4;
  const int n  = t / PER;

  const float* x = X + (size_t)n * IN;
  float ax = 0.f, ay = 0.f, az = 0.f, aw = 0.f;
#pragma unroll
  for (int c = 0; c < IN; ++c) {
    const float xv = x[c];
    const float4 wv = *reinterpret_cast<const float4*>(W + c * OUT + og);
    ax += xv * wv.x; ay += xv * wv.y; az += xv * wv.z; aw += xv * wv.w;
  }
  if (HASBIAS) {
    ax += bias[og + 0]; ay += bias[og + 1]; az += bias[og + 2]; aw += bias[og + 3];
  }
  float4 r; r.x = ax; r.y = ay; r.z = az; r.w = aw;
  *reinterpret_cast<float4*>(H + (size_t)n * OUT + og) = r;
}

// ---------------------------------------------------------------------------
// Kernel 3: GCN aggregation  Y[n,:] = relu((sum_k H[nbr[n,k],:] + H[n,:])/17 + b)
// ---------------------------------------------------------------------------
template <int OUT>
__global__ __launch_bounds__(256) void agg_kernel(const float* __restrict__ H,
                                                  const int* __restrict__ nbr,
                                                  const float* __restrict__ bias,
                                                  float* __restrict__ Y) {
  constexpr int PER = OUT / 4;
  const int t = blockIdx.x * 256 + (int)threadIdx.x;
  if (t >= BATCH * NN * PER) return;
  const int og = (t % PER) * 4;
  const int n  = t / PER;
  const int b  = n >> 11;  // n / NN

  const int* nb = nbr + (size_t)n * KNN;
  const float* Hb = H + (((size_t)b) << 11) * OUT;

  float sx = 0.f, sy = 0.f, sz = 0.f, sw = 0.f;
#pragma unroll
  for (int k = 0; k < KNN; ++k) {
    const int idx = nb[k];
    const float4 v = *reinterpret_cast<const float4*>(Hb + (size_t)idx * OUT + og);
    sx += v.x; sy += v.y; sz += v.z; sw += v.w;
  }
  const float4 h = *reinterpret_cast<const float4*>(H + (size_t)n * OUT + og);
  sx += h.x; sy += h.y; sz += h.z; sw += h.w;

  const float sc = 1.0f / 17.0f;
  float4 r;
  r.x = fmaxf(sx * sc + bias[og + 0], 0.f);
  r.y = fmaxf(sy * sc + bias[og + 1], 0.f);
  r.z = fmaxf(sz * sc + bias[og + 2], 0.f);
  r.w = fmaxf(sw * sc + bias[og + 3], 0.f);
  *reinterpret_cast<float4*>(Y + (size_t)n * OUT + og) = r;
}

// ---------------------------------------------------------------------------
extern "C" void kernel_launch(void* const* d_in, const int* in_sizes, int n_in,
                              void* d_out, int out_size, void* d_ws, size_t ws_size,
                              hipStream_t stream) {
  const float* coords = (const float*)d_in[0];
  const float* W1 = (const float*)d_in[1];
  const float* b1 = (const float*)d_in[2];
  const float* W2 = (const float*)d_in[3];
  const float* b2 = (const float*)d_in[4];
  const float* Wf = (const float*)d_in[5];
  const float* bf = (const float*)d_in[6];
  float* out = (float*)d_out;

  char* ws = (char*)d_ws;
  int*   nbr = (int*)ws;
  float* h1  = (float*)(ws + (size_t)(1u << 20) * 1);
  float* x1  = (float*)(ws + (size_t)(1u << 20) * 5);
  float* h2  = (float*)(ws + (size_t)(1u << 20) * 9);
  float* x2  = (float*)(ws + (size_t)(1u << 20) * 17);

  const int totalN = BATCH * NN;  // 16384

  // one wave per node: 4 nodes / block, 512 blocks / sample
  knn_kernel<<<BATCH * (NN / 4), 256, 0, stream>>>(coords, nbr);

  matmul_kernel<6, 64, false><<<(totalN * (64 / 4)) / 256, 256, 0, stream>>>(coords, W1, nullptr, h1);
  agg_kernel<64><<<(totalN * (64 / 4)) / 256, 256, 0, stream>>>(h1, nbr, b1, x1);

  matmul_kernel<64, 128, false><<<(totalN * (128 / 4)) / 256, 256, 0, stream>>>(x1, W2, nullptr, h2);
  agg_kernel<128><<<(totalN * (128 / 4)) / 256, 256, 0, stream>>>(h2, nbr, b2, x2);

  matmul_kernel<128, 128, true><<<(totalN * (128 / 4)) / 256, 256, 0, stream>>>(x2, Wf, bf, out);
}

// Round 3
// 167.793 us; speedup vs baseline: 5.9818x; 1.4494x over previous
//
#include <hip/hip_runtime.h>

#define NN    2048   // nodes per sample
#define KNN   16     // neighbors
#define BATCH 8

// ---------------------------------------------------------------------------
// cross-lane helpers
// ---------------------------------------------------------------------------
__device__ __forceinline__ unsigned long long bcast64(unsigned long long v, int l) {
  unsigned lo = __builtin_amdgcn_readlane((unsigned)(v & 0xffffffffu), l);
  unsigned hi = __builtin_amdgcn_readlane((unsigned)(v >> 32), l);
  return ((unsigned long long)hi << 32) | lo;
}

// per-16-lane-row shift up by 1 (lane l <- lane l-1), lane 0 of each row -> 0.
// Pure-VALU DPP (row_shr:1 = 0x111); old=0 so invalid lanes produce the 0
// sentinel under either bound_ctrl interpretation.
__device__ __forceinline__ unsigned long long dpp_shr1_zero(unsigned long long v) {
  int lo = __builtin_amdgcn_update_dpp(0, (int)(unsigned)(v & 0xffffffffu), 0x111, 0xf, 0xf, true);
  int hi = __builtin_amdgcn_update_dpp(0, (int)(unsigned)(v >> 32),        0x111, 0xf, 0xf, true);
  return ((unsigned long long)(unsigned)hi << 32) | (unsigned)lo;
}

// ---------------------------------------------------------------------------
// Kernel 1: exact kNN (K=16), one WAVE per node, 8 waves/block (shared LDS),
// fused with GCN layer 1 (aggregate coords in 6-dim, then 6x64 matmul).
// List distributed over lanes 0..15, key = (sortable(d2)<<32)|j.
// Insertion = DPP row-shift + u64 min/max selects (~10 VALU, no LDS path).
// ---------------------------------------------------------------------------
__global__ __launch_bounds__(512) void knn_l1_kernel(const float* __restrict__ coords,
                                                     const float* __restrict__ W1,
                                                     const float* __restrict__ b1,
                                                     int* __restrict__ nbr,
                                                     float* __restrict__ x1) {
  __shared__ float4 sP[NN];  // x,y,z,|p|^2  (32 KB)

  const int b        = blockIdx.x >> 8;          // 256 blocks per sample
  const int nodeBase = (blockIdx.x & 255) << 3;  // 8 nodes per block
  const int lane     = (int)threadIdx.x & 63;
  const int wid      = (int)threadIdx.x >> 6;

  const float* cb = coords + (size_t)b * NN * 6;
  for (int p = threadIdx.x; p < NN; p += 512) {
    const float2 v01 = *reinterpret_cast<const float2*>(cb + p * 6);      // 8B aligned (24B rows)
    const float2 v23 = *reinterpret_cast<const float2*>(cb + p * 6 + 2);
    float4 v; v.x = v01.x; v.y = v01.y; v.z = v23.x;
    v.w = v.x * v.x + v.y * v.y + v.z * v.z;
    sP[p] = v;
  }
  __syncthreads();

  const int i = nodeBase + wid;
  const float4 pi = sP[i];

  unsigned long long lk  = ~0ull;  // lane k (k<16): k-th smallest key
  unsigned long long kth = ~0ull;  // broadcast of lane 15

  for (int t0 = 0; t0 < NN; t0 += 64) {
    const int j = t0 + lane;
    const float4 pj = sP[j];
    const float d2 = (pi.w + pj.w) - 2.0f * (pi.x * pj.x + pi.y * pj.y + pi.z * pj.z);
    unsigned u   = __float_as_uint(d2);
    unsigned k32 = u ^ (unsigned)((((int)u) >> 31) | 0x80000000);
    const unsigned long long ck = ((unsigned long long)k32 << 32) | (unsigned)j;

    unsigned long long mask = __ballot(ck < kth && j != i);
    while (mask) {
      const int src = __ffsll((unsigned long long)mask) - 1;
      mask &= mask - 1;
      const unsigned long long c = bcast64(ck, src);   // wave-uniform
      if (c < kth) {                                   // uniform branch
        const unsigned long long pk = dpp_shr1_zero(lk);
        lk  = (lk < c) ? lk : (pk < c ? c : pk);       // sorted shift-insert
        kth = bcast64(lk, 15);
      }
    }
  }

  const int nj = (int)(lk & 0xffffffffu);
  if (lane < KNN) {
    nbr[((size_t)b * NN + i) * KNN + lane] = nj;
  }

  // ---- fused GCN layer 1: x1[i] = relu( ((sum_nbr c + c_i)/17) @ W1 + b1 ) ----
  float r[6];
#pragma unroll
  for (int c = 0; c < 6; ++c) r[c] = 0.f;
  if (lane < KNN) {
    const float* row = cb + (size_t)nj * 6;
    const float2 a = *reinterpret_cast<const float2*>(row);
    const float2 m = *reinterpret_cast<const float2*>(row + 2);
    const float2 q = *reinterpret_cast<const float2*>(row + 4);
    r[0] = a.x; r[1] = a.y; r[2] = m.x; r[3] = m.y; r[4] = q.x; r[5] = q.y;
  }
  // sum across the 16-lane row (masks 1,2,4,8 stay within the row)
#pragma unroll
  for (int m = 1; m <= 8; m <<= 1) {
#pragma unroll
    for (int c = 0; c < 6; ++c) r[c] += __shfl_xor(r[c], m);
  }
  const float* self = cb + (size_t)i * 6;
  float agg[6];
#pragma unroll
  for (int c = 0; c < 6; ++c) {
    const float nbs = __uint_as_float(__builtin_amdgcn_readfirstlane(__float_as_uint(r[c])));
    agg[c] = (nbs + self[c]) * (1.0f / 17.0f);
  }
  float acc = b1[lane];
#pragma unroll
  for (int c = 0; c < 6; ++c) acc = fmaf(agg[c], W1[c * 64 + lane], acc);
  x1[((size_t)b * NN + i) * 64 + lane] = fmaxf(acc, 0.f);
}

// ---------------------------------------------------------------------------
// Kernel 2/3: fused (aggregate?) + matmul -> 128 outputs (+relu?).
//   GATHER_AGG=true : Y = relu( ((sum_nbr X + X)/17) @ W + bias ),  IN=64
//   GATHER_AGG=false: Y = X @ W + bias,                             IN=128
// 32 nodes/block. Phase A stages (aggregated) rows in LDS; phase B is a
// register-tiled matmul: thread = 4 nodes x 4 outputs, W float4 reused 4x.
// ---------------------------------------------------------------------------
template <int IN, bool GATHER_AGG>
__global__ __launch_bounds__(256) void layer_kernel(const float* __restrict__ X,
                                                    const int* __restrict__ nbr,
                                                    const float* __restrict__ W,
                                                    const float* __restrict__ bias,
                                                    float* __restrict__ Y) {
  constexpr int PAD = 4;
  __shared__ float sA[32][IN + PAD];
  const int t = (int)threadIdx.x;
  const int nodeBase = blockIdx.x * 32;

  if (GATHER_AGG) {
    // thread: node = t/8, dims d0..d0+7  (IN=64)
    constexpr int DPT = IN / 8;  // 8
    const int ln = t >> 3;
    const int d0 = (t & 7) * DPT;
    const int n  = nodeBase + ln;
    const int bs = n >> 11;
    const float* Xb = X + (((size_t)bs) << 11) * IN;
    const int* nb = nbr + (size_t)n * KNN;
    float s[DPT];
#pragma unroll
    for (int d = 0; d < DPT; d += 2) {
      const float2 v = *reinterpret_cast<const float2*>(X + (size_t)n * IN + d0 + d);
      s[d] = v.x; s[d + 1] = v.y;
    }
    for (int k = 0; k < KNN; ++k) {
      const int j = nb[k];
      const float* row = Xb + (size_t)j * IN + d0;
#pragma unroll
      for (int d = 0; d < DPT; d += 2) {
        const float2 v = *reinterpret_cast<const float2*>(row + d);
        s[d] += v.x; s[d + 1] += v.y;
      }
    }
#pragma unroll
    for (int d = 0; d < DPT; ++d) sA[ln][d0 + d] = s[d] * (1.0f / 17.0f);
  } else {
    // IN=128: straight copy, thread copies 16 floats of one row
    const int ln = t >> 3;
    const int d0 = (t & 7) * 16;
    const float* row = X + (size_t)(nodeBase + ln) * IN + d0;
#pragma unroll
    for (int d = 0; d < 16; d += 4)
      *reinterpret_cast<float4*>(&sA[ln][d0 + d]) = *reinterpret_cast<const float4*>(row + d);
  }
  __syncthreads();

  // Phase B: thread -> nodes [ng*4 .. ng*4+3], outputs [og .. og+3]
  const int ng = t >> 5;          // 0..7
  const int og = (t & 31) * 4;    // 0..124
  const float4 bv = *reinterpret_cast<const float4*>(bias + og);
  float4 acc0 = bv, acc1 = bv, acc2 = bv, acc3 = bv;
#pragma unroll 4
  for (int c = 0; c < IN; ++c) {
    const float4 w = *reinterpret_cast<const float4*>(W + (size_t)c * 128 + og);
    const float a0 = sA[ng * 4 + 0][c];
    const float a1 = sA[ng * 4 + 1][c];
    const float a2 = sA[ng * 4 + 2][c];
    const float a3 = sA[ng * 4 + 3][c];
    acc0.x += a0 * w.x; acc0.y += a0 * w.y; acc0.z += a0 * w.z; acc0.w += a0 * w.w;
    acc1.x += a1 * w.x; acc1.y += a1 * w.y; acc1.z += a1 * w.z; acc1.w += a1 * w.w;
    acc2.x += a2 * w.x; acc2.y += a2 * w.y; acc2.z += a2 * w.z; acc2.w += a2 * w.w;
    acc3.x += a3 * w.x; acc3.y += a3 * w.y; acc3.z += a3 * w.z; acc3.w += a3 * w.w;
  }
  float4 accs[4] = {acc0, acc1, acc2, acc3};
#pragma unroll
  for (int q = 0; q < 4; ++q) {
    float4 r = accs[q];
    if (GATHER_AGG) {
      r.x = fmaxf(r.x, 0.f); r.y = fmaxf(r.y, 0.f);
      r.z = fmaxf(r.z, 0.f); r.w = fmaxf(r.w, 0.f);
    }
    const int n = nodeBase + ng * 4 + q;
    *reinterpret_cast<float4*>(&Y[(size_t)n * 128 + og]) = r;
  }
}

// ---------------------------------------------------------------------------
extern "C" void kernel_launch(void* const* d_in, const int* in_sizes, int n_in,
                              void* d_out, int out_size, void* d_ws, size_t ws_size,
                              hipStream_t stream) {
  const float* coords = (const float*)d_in[0];
  const float* W1 = (const float*)d_in[1];
  const float* b1 = (const float*)d_in[2];
  const float* W2 = (const float*)d_in[3];
  const float* b2 = (const float*)d_in[4];
  const float* Wf = (const float*)d_in[5];
  const float* bf = (const float*)d_in[6];
  float* out = (float*)d_out;

  char* ws = (char*)d_ws;
  int*   nbr = (int*)ws;                              // 1 MB
  float* x1  = (float*)(ws + (size_t)(1u << 20) * 1); // 4 MB
  float* x2  = (float*)(ws + (size_t)(1u << 20) * 9); // 8 MB

  // kNN + layer 1: one wave per node, 8 waves/block
  knn_l1_kernel<<<BATCH * (NN / 8), 512, 0, stream>>>(coords, W1, b1, nbr, x1);

  // layer 2: aggregate(64) + matmul 64->128 + relu
  layer_kernel<64, true><<<(BATCH * NN) / 32, 256, 0, stream>>>(x1, nbr, W2, b2, x2);

  // final linear 128->128
  layer_kernel<128, false><<<(BATCH * NN) / 32, 256, 0, stream>>>(x2, nbr, Wf, bf, out);
}

// Round 6
// 150.852 us; speedup vs baseline: 6.6535x; 1.1123x over previous
//
#include <hip/hip_runtime.h>

#define NN    2048   // nodes per sample
#define KNN   16     // neighbors
#define BATCH 8

__device__ __forceinline__ unsigned umin_u(unsigned a, unsigned b) { return a < b ? a : b; }

// ---------------------------------------------------------------------------
// cross-lane helpers
// ---------------------------------------------------------------------------
__device__ __forceinline__ unsigned long long bcast64(unsigned long long v, int l) {
  unsigned lo = __builtin_amdgcn_readlane((unsigned)(v & 0xffffffffu), l);
  unsigned hi = __builtin_amdgcn_readlane((unsigned)(v >> 32), l);
  return ((unsigned long long)hi << 32) | lo;
}

// per-16-lane-row shift up by 1 (lane l <- lane l-1), lane 0 of each row -> 0.
__device__ __forceinline__ unsigned long long dpp_shr1_zero(unsigned long long v) {
  int lo = __builtin_amdgcn_update_dpp(0, (int)(unsigned)(v & 0xffffffffu), 0x111, 0xf, 0xf, true);
  int hi = __builtin_amdgcn_update_dpp(0, (int)(unsigned)(v >> 32),        0x111, 0xf, 0xf, true);
  return ((unsigned long long)(unsigned)hi << 32) | (unsigned)lo;
}

// ---------------------------------------------------------------------------
// Kernel 1: exact kNN (K=16), one WAVE per node, 8 waves/block, fused GCN L1.
// Pass 1: per-lane min d2 -> exact 17th-smallest of the 64 lane-minima (tau);
//         rank 17 absorbs the self-distance. Seeding pass-2's kth with
//         tau+64ulp prunes serial insertions ~94 -> ~25. The 64-ulp slack
//         covers fma-contraction drift between pass-1 and pass-2 d2 values
//         (the R5 failure mode: tau pinned to pass-1 values starved the list
//         at nodes with near-tied 16th/17th distances).
// Pass 2: ballot survivors against running kth; DPP shift-insert into the
//         lane-distributed sorted top-16 (key = sortable(d2)<<32 | j).
//         If the list somehow underfills (sentinel in lane 15), rerun
//         unseeded — exact R3 semantics — so correctness never rests on the
//         slack argument.
// ---------------------------------------------------------------------------
__global__ __launch_bounds__(512) void knn_l1_kernel(const float* __restrict__ coords,
                                                     const float* __restrict__ W1,
                                                     const float* __restrict__ b1,
                                                     int* __restrict__ nbr,
                                                     float* __restrict__ x1) {
  __shared__ float4 sP[NN];  // x,y,z,|p|^2  (32 KB)

  const int b        = blockIdx.x >> 8;          // 256 blocks per sample
  const int nodeBase = (blockIdx.x & 255) << 3;  // 8 nodes per block
  const int lane     = (int)threadIdx.x & 63;
  const int wid      = (int)threadIdx.x >> 6;

  const float* cb = coords + (size_t)b * NN * 6;
  for (int p = threadIdx.x; p < NN; p += 512) {
    const float2 v01 = *reinterpret_cast<const float2*>(cb + p * 6);
    const float2 v23 = *reinterpret_cast<const float2*>(cb + p * 6 + 2);
    float4 v; v.x = v01.x; v.y = v01.y; v.z = v23.x;
    v.w = v.x * v.x + v.y * v.y + v.z * v.z;
    sP[p] = v;
  }
  __syncthreads();

  const int i = nodeBase + wid;
  const float4 pi = sP[i];

  // ---- pass 1: per-lane min distance over this lane's 32 candidates ----
  float lmin = 1e30f;
  for (int t0 = 0; t0 < NN; t0 += 64) {
    const float4 pj = sP[t0 + lane];
    const float d2 = (pi.w + pj.w) - 2.0f * (pi.x * pj.x + pi.y * pj.y + pi.z * pj.z);
    lmin = fminf(lmin, d2);
  }
  unsigned lm = __float_as_uint(lmin);
  lm = lm ^ (unsigned)((((int)lm) >> 31) | 0x80000000);  // monotonic key

  // exact 17th-smallest of the 64 lane keys (bitwise value-select)
  unsigned tau = 0u;
  for (int bit = 31; bit >= 0; --bit) {
    const unsigned t_try = tau + ((1u << bit) - 1u);
    const unsigned long long m = __ballot(lm <= t_try);
    if (__popcll(m) < 17) tau += (1u << bit);
  }
  const unsigned tau_s = (tau >= 0xFFFFFFC0u) ? 0xFFFFFFFFu : tau + 64u;  // +64 ulp slack

  // ---- pass 2: exact top-16 with tau-seeded pruning + exact fallback ----
  unsigned long long lk  = ~0ull;                                   // lane k: k-th best
  unsigned long long kth = ((unsigned long long)tau_s << 32) | 0xFFFFFFFFull;

  for (int attempt = 0; attempt < 2; ++attempt) {
    for (int t0 = 0; t0 < NN; t0 += 64) {
      const int j = t0 + lane;
      const float4 pj = sP[j];
      const float d2 = (pi.w + pj.w) - 2.0f * (pi.x * pj.x + pi.y * pj.y + pi.z * pj.z);
      unsigned u   = __float_as_uint(d2);
      unsigned k32 = u ^ (unsigned)((((int)u) >> 31) | 0x80000000);
      const unsigned long long ck = ((unsigned long long)k32 << 32) | (unsigned)j;

      unsigned long long mask = __ballot(ck < kth && j != i);
      while (mask) {
        const int src = __ffsll((unsigned long long)mask) - 1;
        mask &= mask - 1;
        const unsigned long long c = bcast64(ck, src);   // wave-uniform
        if (c < kth) {                                   // uniform branch
          const unsigned long long pk = dpp_shr1_zero(lk);
          lk = (lk < c) ? lk : (pk < c ? c : pk);        // sorted shift-insert
          const unsigned long long nk = bcast64(lk, 15);
          kth = (nk < kth) ? nk : kth;                   // monotone tighten
        }
      }
    }
    if (bcast64(lk, 15) != ~0ull) break;  // 16 real entries -> done (uniform)
    lk = ~0ull; kth = ~0ull;              // rare: rerun unseeded (exact, R3 path)
  }

  // clamped index: a sentinel can never reach memory
  const int nj = (int)umin_u((unsigned)(lk & 0xffffffffu), NN - 1u);
  if (lane < KNN) {
    nbr[((size_t)b * NN + i) * KNN + lane] = nj;
  }

  // ---- fused GCN layer 1: x1[i] = relu( ((sum_nbr c + c_i)/17) @ W1 + b1 ) ----
  float r[6];
#pragma unroll
  for (int c = 0; c < 6; ++c) r[c] = 0.f;
  if (lane < KNN) {
    const float* row = cb + (size_t)nj * 6;
    const float2 a = *reinterpret_cast<const float2*>(row);
    const float2 m = *reinterpret_cast<const float2*>(row + 2);
    const float2 q = *reinterpret_cast<const float2*>(row + 4);
    r[0] = a.x; r[1] = a.y; r[2] = m.x; r[3] = m.y; r[4] = q.x; r[5] = q.y;
  }
#pragma unroll
  for (int m = 1; m <= 8; m <<= 1) {
#pragma unroll
    for (int c = 0; c < 6; ++c) r[c] += __shfl_xor(r[c], m);
  }
  const float* self = cb + (size_t)i * 6;
  float agg[6];
#pragma unroll
  for (int c = 0; c < 6; ++c) {
    const float nbs = __uint_as_float(__builtin_amdgcn_readfirstlane(__float_as_uint(r[c])));
    agg[c] = (nbs + self[c]) * (1.0f / 17.0f);
  }
  float acc = b1[lane];
#pragma unroll
  for (int c = 0; c < 6; ++c) acc = fmaf(agg[c], W1[c * 64 + lane], acc);
  x1[((size_t)b * NN + i) * 64 + lane] = fmaxf(acc, 0.f);
}

// ---------------------------------------------------------------------------
// Kernel 2: fused GCN layer 2 + final Linear.
//   sA = (sum_nbr x1 + x1)/17   ;  sB = relu(sA @ W2 + b2)  ;  out = sB @ Wf + bf
// 16 nodes / 256 threads; thread = (node, 8 outputs). x2 never touches HBM.
// ---------------------------------------------------------------------------
__global__ __launch_bounds__(256) void layers_kernel(const float* __restrict__ x1,
                                                     const int* __restrict__ nbr,
                                                     const float* __restrict__ W2,
                                                     const float* __restrict__ b2,
                                                     const float* __restrict__ Wf,
                                                     const float* __restrict__ bf,
                                                     float* __restrict__ out) {
  __shared__ float sA[16][68];    // aggregated x1 (pad 4)
  __shared__ float sB[16][132];   // x2 tile      (pad 4)
  __shared__ int   sN[16][16];

  const int t        = (int)threadIdx.x;
  const int nodeBase = blockIdx.x * 16;
  const int bs       = nodeBase >> 11;          // sample index
  const int ln       = t >> 4;                  // node in tile 0..15
  const int lo       = t & 15;

  // consumer-side clamp (belt & braces; producer already clamps)
  sN[ln][lo] = (int)umin_u((unsigned)nbr[(size_t)(nodeBase + ln) * KNN + lo], NN - 1u);
  __syncthreads();

  // Phase A: gather-aggregate x1 (each thread: one node, 4 dims)
  {
    const int d4 = lo * 4;
    const int n  = nodeBase + ln;
    const float* Xb = x1 + (((size_t)bs) << 11) * 64;
    float4 s = *reinterpret_cast<const float4*>(x1 + (size_t)n * 64 + d4);
#pragma unroll
    for (int k = 0; k < KNN; ++k) {
      const int j = sN[ln][k];
      const float4 v = *reinterpret_cast<const float4*>(Xb + (size_t)j * 64 + d4);
      s.x += v.x; s.y += v.y; s.z += v.z; s.w += v.w;
    }
    const float sc = 1.0f / 17.0f;
    sA[ln][d4 + 0] = s.x * sc; sA[ln][d4 + 1] = s.y * sc;
    sA[ln][d4 + 2] = s.z * sc; sA[ln][d4 + 3] = s.w * sc;
  }
  __syncthreads();

  const int o8 = lo * 8;

  // Phase B: x2 = relu(sA @ W2 + b2) -> sB
  {
    const float4 bv0 = *reinterpret_cast<const float4*>(b2 + o8);
    const float4 bv1 = *reinterpret_cast<const float4*>(b2 + o8 + 4);
    float a0 = bv0.x, a1 = bv0.y, a2 = bv0.z, a3 = bv0.w;
    float a4 = bv1.x, a5 = bv1.y, a6 = bv1.z, a7 = bv1.w;
#pragma unroll 4
    for (int c = 0; c < 64; ++c) {
      const float a = sA[ln][c];
      const float4 w0 = *reinterpret_cast<const float4*>(W2 + (size_t)c * 128 + o8);
      const float4 w1 = *reinterpret_cast<const float4*>(W2 + (size_t)c * 128 + o8 + 4);
      a0 += a * w0.x; a1 += a * w0.y; a2 += a * w0.z; a3 += a * w0.w;
      a4 += a * w1.x; a5 += a * w1.y; a6 += a * w1.z; a7 += a * w1.w;
    }
    sB[ln][o8 + 0] = fmaxf(a0, 0.f); sB[ln][o8 + 1] = fmaxf(a1, 0.f);
    sB[ln][o8 + 2] = fmaxf(a2, 0.f); sB[ln][o8 + 3] = fmaxf(a3, 0.f);
    sB[ln][o8 + 4] = fmaxf(a4, 0.f); sB[ln][o8 + 5] = fmaxf(a5, 0.f);
    sB[ln][o8 + 6] = fmaxf(a6, 0.f); sB[ln][o8 + 7] = fmaxf(a7, 0.f);
  }
  __syncthreads();

  // Phase C: out = sB @ Wf + bf
  {
    const float4 bv0 = *reinterpret_cast<const float4*>(bf + o8);
    const float4 bv1 = *reinterpret_cast<const float4*>(bf + o8 + 4);
    float a0 = bv0.x, a1 = bv0.y, a2 = bv0.z, a3 = bv0.w;
    float a4 = bv1.x, a5 = bv1.y, a6 = bv1.z, a7 = bv1.w;
#pragma unroll 4
    for (int c = 0; c < 128; ++c) {
      const float a = sB[ln][c];
      const float4 w0 = *reinterpret_cast<const float4*>(Wf + (size_t)c * 128 + o8);
      const float4 w1 = *reinterpret_cast<const float4*>(Wf + (size_t)c * 128 + o8 + 4);
      a0 += a * w0.x; a1 += a * w0.y; a2 += a * w0.z; a3 += a * w0.w;
      a4 += a * w1.x; a5 += a * w1.y; a6 += a * w1.z; a7 += a * w1.w;
    }
    float* o = out + (size_t)(nodeBase + ln) * 128 + o8;
    float4 r0; r0.x = a0; r0.y = a1; r0.z = a2; r0.w = a3;
    float4 r1; r1.x = a4; r1.y = a5; r1.z = a6; r1.w = a7;
    *reinterpret_cast<float4*>(o)     = r0;
    *reinterpret_cast<float4*>(o + 4) = r1;
  }
}

// ---------------------------------------------------------------------------
extern "C" void kernel_launch(void* const* d_in, const int* in_sizes, int n_in,
                              void* d_out, int out_size, void* d_ws, size_t ws_size,
                              hipStream_t stream) {
  const float* coords = (const float*)d_in[0];
  const float* W1 = (const float*)d_in[1];
  const float* b1 = (const float*)d_in[2];
  const float* W2 = (const float*)d_in[3];
  const float* b2 = (const float*)d_in[4];
  const float* Wf = (const float*)d_in[5];
  const float* bf = (const float*)d_in[6];
  float* out = (float*)d_out;

  char* ws = (char*)d_ws;
  int*   nbr = (int*)ws;                              // 1 MB
  float* x1  = (float*)(ws + (size_t)(1u << 20) * 1); // 4 MB

  // kNN + layer 1: one wave per node, 8 waves/block
  knn_l1_kernel<<<BATCH * (NN / 8), 512, 0, stream>>>(coords, W1, b1, nbr, x1);

  // layer 2 (aggregate + 64->128 + relu) fused with final 128->128 linear
  layers_kernel<<<(BATCH * NN) / 16, 256, 0, stream>>>(x1, nbr, W2, b2, Wf, bf, out);
}

// Round 7
// 123.388 us; speedup vs baseline: 8.1344x; 1.2226x over previous
//
#include <hip/hip_runtime.h>

#define NN    2048   // nodes per sample
#define KNN   16     // neighbors
#define BATCH 8

__device__ __forceinline__ unsigned umin_u(unsigned a, unsigned b) { return a < b ? a : b; }

// ---------------------------------------------------------------------------
// cross-lane helpers
// ---------------------------------------------------------------------------
__device__ __forceinline__ unsigned long long bcast64(unsigned long long v, int l) {
  unsigned lo = __builtin_amdgcn_readlane((unsigned)(v & 0xffffffffu), l);
  unsigned hi = __builtin_amdgcn_readlane((unsigned)(v >> 32), l);
  return ((unsigned long long)hi << 32) | lo;
}

// per-16-lane-row shift up by 1 (lane l <- lane l-1), lane 0 of each row -> 0.
__device__ __forceinline__ unsigned long long dpp_shr1_zero(unsigned long long v) {
  int lo = __builtin_amdgcn_update_dpp(0, (int)(unsigned)(v & 0xffffffffu), 0x111, 0xf, 0xf, true);
  int hi = __builtin_amdgcn_update_dpp(0, (int)(unsigned)(v >> 32),        0x111, 0xf, 0xf, true);
  return ((unsigned long long)(unsigned)hi << 32) | (unsigned)lo;
}

// ---------------------------------------------------------------------------
// Kernel 1: exact kNN (K=16), one WAVE per node, 8 waves/block, fused GCN L1.
// (unchanged from R6 — passed with absmax at the bf16 floor)
// ---------------------------------------------------------------------------
__global__ __launch_bounds__(512) void knn_l1_kernel(const float* __restrict__ coords,
                                                     const float* __restrict__ W1,
                                                     const float* __restrict__ b1,
                                                     int* __restrict__ nbr,
                                                     float* __restrict__ x1) {
  __shared__ float4 sP[NN];  // x,y,z,|p|^2  (32 KB)

  const int b        = blockIdx.x >> 8;          // 256 blocks per sample
  const int nodeBase = (blockIdx.x & 255) << 3;  // 8 nodes per block
  const int lane     = (int)threadIdx.x & 63;
  const int wid      = (int)threadIdx.x >> 6;

  const float* cb = coords + (size_t)b * NN * 6;
  for (int p = threadIdx.x; p < NN; p += 512) {
    const float2 v01 = *reinterpret_cast<const float2*>(cb + p * 6);
    const float2 v23 = *reinterpret_cast<const float2*>(cb + p * 6 + 2);
    float4 v; v.x = v01.x; v.y = v01.y; v.z = v23.x;
    v.w = v.x * v.x + v.y * v.y + v.z * v.z;
    sP[p] = v;
  }
  __syncthreads();

  const int i = nodeBase + wid;
  const float4 pi = sP[i];

  // ---- pass 1: per-lane min distance over this lane's 32 candidates ----
  float lmin = 1e30f;
  for (int t0 = 0; t0 < NN; t0 += 64) {
    const float4 pj = sP[t0 + lane];
    const float d2 = (pi.w + pj.w) - 2.0f * (pi.x * pj.x + pi.y * pj.y + pi.z * pj.z);
    lmin = fminf(lmin, d2);
  }
  unsigned lm = __float_as_uint(lmin);
  lm = lm ^ (unsigned)((((int)lm) >> 31) | 0x80000000);  // monotonic key

  // exact 17th-smallest of the 64 lane keys (bitwise value-select)
  unsigned tau = 0u;
  for (int bit = 31; bit >= 0; --bit) {
    const unsigned t_try = tau + ((1u << bit) - 1u);
    const unsigned long long m = __ballot(lm <= t_try);
    if (__popcll(m) < 17) tau += (1u << bit);
  }
  const unsigned tau_s = (tau >= 0xFFFFFFC0u) ? 0xFFFFFFFFu : tau + 64u;  // +64 ulp slack

  // ---- pass 2: exact top-16 with tau-seeded pruning + exact fallback ----
  unsigned long long lk  = ~0ull;                                   // lane k: k-th best
  unsigned long long kth = ((unsigned long long)tau_s << 32) | 0xFFFFFFFFull;

  for (int attempt = 0; attempt < 2; ++attempt) {
    for (int t0 = 0; t0 < NN; t0 += 64) {
      const int j = t0 + lane;
      const float4 pj = sP[j];
      const float d2 = (pi.w + pj.w) - 2.0f * (pi.x * pj.x + pi.y * pj.y + pi.z * pj.z);
      unsigned u   = __float_as_uint(d2);
      unsigned k32 = u ^ (unsigned)((((int)u) >> 31) | 0x80000000);
      const unsigned long long ck = ((unsigned long long)k32 << 32) | (unsigned)j;

      unsigned long long mask = __ballot(ck < kth && j != i);
      while (mask) {
        const int src = __ffsll((unsigned long long)mask) - 1;
        mask &= mask - 1;
        const unsigned long long c = bcast64(ck, src);   // wave-uniform
        if (c < kth) {                                   // uniform branch
          const unsigned long long pk = dpp_shr1_zero(lk);
          lk = (lk < c) ? lk : (pk < c ? c : pk);        // sorted shift-insert
          const unsigned long long nk = bcast64(lk, 15);
          kth = (nk < kth) ? nk : kth;                   // monotone tighten
        }
      }
    }
    if (bcast64(lk, 15) != ~0ull) break;  // 16 real entries -> done (uniform)
    lk = ~0ull; kth = ~0ull;              // rare: rerun unseeded (exact path)
  }

  // clamped index: a sentinel can never reach memory
  const int nj = (int)umin_u((unsigned)(lk & 0xffffffffu), NN - 1u);
  if (lane < KNN) {
    nbr[((size_t)b * NN + i) * KNN + lane] = nj;
  }

  // ---- fused GCN layer 1: x1[i] = relu( ((sum_nbr c + c_i)/17) @ W1 + b1 ) ----
  float r[6];
#pragma unroll
  for (int c = 0; c < 6; ++c) r[c] = 0.f;
  if (lane < KNN) {
    const float* row = cb + (size_t)nj * 6;
    const float2 a = *reinterpret_cast<const float2*>(row);
    const float2 m = *reinterpret_cast<const float2*>(row + 2);
    const float2 q = *reinterpret_cast<const float2*>(row + 4);
    r[0] = a.x; r[1] = a.y; r[2] = m.x; r[3] = m.y; r[4] = q.x; r[5] = q.y;
  }
#pragma unroll
  for (int m = 1; m <= 8; m <<= 1) {
#pragma unroll
    for (int c = 0; c < 6; ++c) r[c] += __shfl_xor(r[c], m);
  }
  const float* self = cb + (size_t)i * 6;
  float agg[6];
#pragma unroll
  for (int c = 0; c < 6; ++c) {
    const float nbs = __uint_as_float(__builtin_amdgcn_readfirstlane(__float_as_uint(r[c])));
    agg[c] = (nbs + self[c]) * (1.0f / 17.0f);
  }
  float acc = b1[lane];
#pragma unroll
  for (int c = 0; c < 6; ++c) acc = fmaf(agg[c], W1[c * 64 + lane], acc);
  x1[((size_t)b * NN + i) * 64 + lane] = fmaxf(acc, 0.f);
}

// ---------------------------------------------------------------------------
// Kernel 2: fused GCN layer 2 + final Linear, register-tiled.
//   sA = (sum_nbr x1 + x1)/17 ; sB = relu(sA @ W2 + b2) ; out = sB @ Wf + bf
// 32 nodes / 256 threads / block (512 blocks). Phases B/C: thread = 4 nodes x
// 4 outputs -> each W float4 feeds 16 FMAs (4x less W cache traffic than the
// R6 1-node layout, whose L1 volume ~matched the 53.5us measured), and 16
// independent acc chains give ILP for latency hiding. sA/sB reads are
// 32-lane broadcasts; W loads are 512B/wave unique.
// ---------------------------------------------------------------------------
__global__ __launch_bounds__(256) void layers_kernel(const float* __restrict__ x1,
                                                     const int* __restrict__ nbr,
                                                     const float* __restrict__ W2,
                                                     const float* __restrict__ b2,
                                                     const float* __restrict__ Wf,
                                                     const float* __restrict__ bf,
                                                     float* __restrict__ out) {
  __shared__ float sA[32][68];    // aggregated x1 (pad 4)
  __shared__ float sB[32][132];   // x2 tile      (pad 4)
  __shared__ int   sN[512];

  const int t        = (int)threadIdx.x;
  const int nodeBase = blockIdx.x * 32;
  const int bs       = nodeBase >> 11;          // sample index (32 | 2048)

  // neighbor lists for 32 nodes (clamped: sentinel can never reach memory)
  sN[t]       = (int)umin_u((unsigned)nbr[(size_t)nodeBase * KNN + t],       NN - 1u);
  sN[t + 256] = (int)umin_u((unsigned)nbr[(size_t)nodeBase * KNN + t + 256], NN - 1u);
  __syncthreads();

  // Phase A: gather-aggregate x1 (thread = node t>>3, dims (t&7)*8 .. +7)
  {
    const int ln = t >> 3;
    const int d8 = (t & 7) * 8;
    const int n  = nodeBase + ln;
    const float* Xb = x1 + (((size_t)bs) << 11) * 64;
    const float* xn = x1 + (size_t)n * 64 + d8;
    float4 s0 = *reinterpret_cast<const float4*>(xn);
    float4 s1 = *reinterpret_cast<const float4*>(xn + 4);
    const int* nb = &sN[ln * 16];
#pragma unroll
    for (int k = 0; k < KNN; ++k) {
      const float* row = Xb + (size_t)nb[k] * 64 + d8;
      const float4 v0 = *reinterpret_cast<const float4*>(row);
      const float4 v1 = *reinterpret_cast<const float4*>(row + 4);
      s0.x += v0.x; s0.y += v0.y; s0.z += v0.z; s0.w += v0.w;
      s1.x += v1.x; s1.y += v1.y; s1.z += v1.z; s1.w += v1.w;
    }
    const float sc = 1.0f / 17.0f;
    sA[ln][d8 + 0] = s0.x * sc; sA[ln][d8 + 1] = s0.y * sc;
    sA[ln][d8 + 2] = s0.z * sc; sA[ln][d8 + 3] = s0.w * sc;
    sA[ln][d8 + 4] = s1.x * sc; sA[ln][d8 + 5] = s1.y * sc;
    sA[ln][d8 + 6] = s1.z * sc; sA[ln][d8 + 7] = s1.w * sc;
  }
  __syncthreads();

  const int ng = (t >> 5) * 4;   // first of 4 nodes
  const int o4 = (t & 31) * 4;   // 4 outputs

  // Phase B: x2 = relu(sA @ W2 + b2) -> sB  (K=64)
  {
    const float4 bv = *reinterpret_cast<const float4*>(b2 + o4);
    float4 acc0 = bv, acc1 = bv, acc2 = bv, acc3 = bv;
#pragma unroll 4
    for (int c = 0; c < 64; ++c) {
      const float4 w = *reinterpret_cast<const float4*>(W2 + (size_t)c * 128 + o4);
      const float a0 = sA[ng + 0][c];
      const float a1 = sA[ng + 1][c];
      const float a2 = sA[ng + 2][c];
      const float a3 = sA[ng + 3][c];
      acc0.x += a0 * w.x; acc0.y += a0 * w.y; acc0.z += a0 * w.z; acc0.w += a0 * w.w;
      acc1.x += a1 * w.x; acc1.y += a1 * w.y; acc1.z += a1 * w.z; acc1.w += a1 * w.w;
      acc2.x += a2 * w.x; acc2.y += a2 * w.y; acc2.z += a2 * w.z; acc2.w += a2 * w.w;
      acc3.x += a3 * w.x; acc3.y += a3 * w.y; acc3.z += a3 * w.z; acc3.w += a3 * w.w;
    }
    sB[ng + 0][o4 + 0] = fmaxf(acc0.x, 0.f); sB[ng + 0][o4 + 1] = fmaxf(acc0.y, 0.f);
    sB[ng + 0][o4 + 2] = fmaxf(acc0.z, 0.f); sB[ng + 0][o4 + 3] = fmaxf(acc0.w, 0.f);
    sB[ng + 1][o4 + 0] = fmaxf(acc1.x, 0.f); sB[ng + 1][o4 + 1] = fmaxf(acc1.y, 0.f);
    sB[ng + 1][o4 + 2] = fmaxf(acc1.z, 0.f); sB[ng + 1][o4 + 3] = fmaxf(acc1.w, 0.f);
    sB[ng + 2][o4 + 0] = fmaxf(acc2.x, 0.f); sB[ng + 2][o4 + 1] = fmaxf(acc2.y, 0.f);
    sB[ng + 2][o4 + 2] = fmaxf(acc2.z, 0.f); sB[ng + 2][o4 + 3] = fmaxf(acc2.w, 0.f);
    sB[ng + 3][o4 + 0] = fmaxf(acc3.x, 0.f); sB[ng + 3][o4 + 1] = fmaxf(acc3.y, 0.f);
    sB[ng + 3][o4 + 2] = fmaxf(acc3.z, 0.f); sB[ng + 3][o4 + 3] = fmaxf(acc3.w, 0.f);
  }
  __syncthreads();

  // Phase C: out = sB @ Wf + bf  (K=128)
  {
    const float4 bv = *reinterpret_cast<const float4*>(bf + o4);
    float4 acc0 = bv, acc1 = bv, acc2 = bv, acc3 = bv;
#pragma unroll 4
    for (int c = 0; c < 128; ++c) {
      const float4 w = *reinterpret_cast<const float4*>(Wf + (size_t)c * 128 + o4);
      const float a0 = sB[ng + 0][c];
      const float a1 = sB[ng + 1][c];
      const float a2 = sB[ng + 2][c];
      const float a3 = sB[ng + 3][c];
      acc0.x += a0 * w.x; acc0.y += a0 * w.y; acc0.z += a0 * w.z; acc0.w += a0 * w.w;
      acc1.x += a1 * w.x; acc1.y += a1 * w.y; acc1.z += a1 * w.z; acc1.w += a1 * w.w;
      acc2.x += a2 * w.x; acc2.y += a2 * w.y; acc2.z += a2 * w.z; acc2.w += a2 * w.w;
      acc3.x += a3 * w.x; acc3.y += a3 * w.y; acc3.z += a3 * w.z; acc3.w += a3 * w.w;
    }
    float* o0 = out + (size_t)(nodeBase + ng) * 128 + o4;
    *reinterpret_cast<float4*>(o0)           = acc0;
    *reinterpret_cast<float4*>(o0 + 128)     = acc1;
    *reinterpret_cast<float4*>(o0 + 256)     = acc2;
    *reinterpret_cast<float4*>(o0 + 384)     = acc3;
  }
}

// ---------------------------------------------------------------------------
extern "C" void kernel_launch(void* const* d_in, const int* in_sizes, int n_in,
                              void* d_out, int out_size, void* d_ws, size_t ws_size,
                              hipStream_t stream) {
  const float* coords = (const float*)d_in[0];
  const float* W1 = (const float*)d_in[1];
  const float* b1 = (const float*)d_in[2];
  const float* W2 = (const float*)d_in[3];
  const float* b2 = (const float*)d_in[4];
  const float* Wf = (const float*)d_in[5];
  const float* bf = (const float*)d_in[6];
  float* out = (float*)d_out;

  char* ws = (char*)d_ws;
  int*   nbr = (int*)ws;                              // 1 MB
  float* x1  = (float*)(ws + (size_t)(1u << 20) * 1); // 4 MB

  // kNN + layer 1: one wave per node, 8 waves/block
  knn_l1_kernel<<<BATCH * (NN / 8), 512, 0, stream>>>(coords, W1, b1, nbr, x1);

  // layer 2 (aggregate + 64->128 + relu) fused with final 128->128 linear
  layers_kernel<<<(BATCH * NN) / 32, 256, 0, stream>>>(x1, nbr, W2, b2, Wf, bf, out);
}